// Round 9
// baseline (32.207 us; speedup 1.0000x reference)
//
#include <hip/hip_runtime.h>

// DivEncLayer via MFMA — r6 compute core, ZERO in-loop barriers/stores.
// Per (b,q): h = elu(x[b,q*8:+8]@W1[q] + b1[q]); LN(h); out = h@W2[q]+b2[q].
// B=16384, Q=128, S=8, U=32.
//
// v_mfma_f32_32x32x16_bf16 operand mapping (validated rounds 2-8):
//   A: lane l, reg j -> A[l&31][j + 8*(l>>5)]
//   B: lane l, reg j -> B[j + 8*(l>>5)][l&31]
//   D: lane l, reg r -> row u=(r&3)+8*(r>>2)+4*(l>>5), col b=l&31
// Packed A-frag: lanes<32 = bf16(W1^T) (k=0..7), lanes>=32 = bf16(W1-hi) (k=8..15).
// B duplicates each row across lane-halves (addressed by u=ln&31):
// D = (whi+wlo)*xhi + C-in, C-in = b1 (fp32 exact). x is bf16-hi only.
// LN+Dense2 folded: out = rsqrt(var+eps)*(dot(e,g2) - mu*G) + C.
//
// Stall fix (r8 post-mortem): the per-iter __syncthreads forced
// s_waitcnt vmcnt(0) -> drained the prefetch AND waited store-acks every
// iteration. Now: loop = load->cvt->MFMA->finish->ds_write only (no barrier,
// no global store). ONE barrier after the loop, then a gather/store phase.
// Block = 4 waves = 4 consecutive q, 8 iters x 64 contiguous rows.
// Grid (32,32) = 1024 blocks.

typedef __attribute__((ext_vector_type(8))) short short8;    // 8 bf16
typedef __attribute__((ext_vector_type(16))) float f32x16;

__device__ __forceinline__ short fbits(__bf16 b) { return __builtin_bit_cast(short, b); }

__device__ __forceinline__ float elu1(float v) {
    return v > 0.f ? v : __expf(v) - 1.f;
}

__device__ __forceinline__ short8 cvt8(const float4& a, const float4& b) {
    short8 r;
    r[0] = fbits((__bf16)a.x); r[1] = fbits((__bf16)a.y);
    r[2] = fbits((__bf16)a.z); r[3] = fbits((__bf16)a.w);
    r[4] = fbits((__bf16)b.x); r[5] = fbits((__bf16)b.y);
    r[6] = fbits((__bf16)b.z); r[7] = fbits((__bf16)b.w);
    return r;
}

__device__ __forceinline__ float finish(const f32x16& acc, const f32x16& g2r,
                                        float G, float C) {
    float sum = 0.f, ss = 0.f, dot = 0.f;
    #pragma unroll
    for (int r = 0; r < 16; ++r) {
        float e = elu1(acc[r]);
        sum += e;
        ss  = fmaf(e, e, ss);
        dot = fmaf(e, g2r[r], dot);
    }
    sum += __shfl_xor(sum, 32);
    ss  += __shfl_xor(ss, 32);
    dot += __shfl_xor(dot, 32);
    float mu  = sum * 0.03125f;
    float var = fmaf(-mu, mu, ss * 0.03125f);
    float inv = rsqrtf(var + 1e-3f);
    return fmaf(inv, fmaf(-mu, G, dot), C);
}

__global__ __launch_bounds__(256, 4) void divenc_mfma(
    const float* __restrict__ x,      // (16384, 1024)
    const float* __restrict__ W1,     // (128, 8, 32)
    const float* __restrict__ b1,     // (128, 32)
    const float* __restrict__ gamma,  // (128, 32)
    const float* __restrict__ beta,   // (128, 32)
    const float* __restrict__ W2,     // (128, 32)
    const float* __restrict__ b2,     // (128,)
    float* __restrict__ out)          // (16384, 128)
{
    __shared__ float lout[512 * 5];   // [row][q-slot], stride 5 (10 KiB)

    const int tid  = threadIdx.x;
    const int w    = tid >> 6;
    const int ln   = tid & 63;
    const int u    = ln & 31;
    const int half = ln >> 5;
    const int qt   = blockIdx.y;      // 0..31
    const int q    = qt * 4 + w;
    const int bx   = blockIdx.x;      // 0..31; block covers rows bx*512..+511

    // ---- A-frag: lanes<32 = whi (k=0..7), lanes>=32 = wlo (k=8..15) ----
    short8 wfrag;
    #pragma unroll
    for (int j = 0; j < 8; ++j) {
        float f  = W1[q * 256 + j * 32 + u];
        __bf16 h = (__bf16)f;
        wfrag[j] = half ? fbits((__bf16)(f - (float)h)) : fbits(h);
    }

    // ---- params: biasr (MFMA C-in) + g2r in regs, vector loads ----
    f32x16 biasr, g2r;
    float G, C;
    {
        float gs = 0.f, cs = 0.f;
        #pragma unroll
        for (int c = 0; c < 4; ++c) {
            const int ub = q * 32 + 4 * half + 8 * c;
            float4 b1v = *(const float4*)&b1[ub];
            float4 gav = *(const float4*)&gamma[ub];
            float4 w2v = *(const float4*)&W2[ub];
            float4 bev = *(const float4*)&beta[ub];
            #pragma unroll
            for (int j = 0; j < 4; ++j) {
                float g2 = ((const float*)&gav)[j] * ((const float*)&w2v)[j];
                biasr[4 * c + j] = ((const float*)&b1v)[j];
                g2r[4 * c + j]   = g2;
                gs += g2;
                cs += ((const float*)&bev)[j] * ((const float*)&w2v)[j];
            }
        }
        gs += __shfl_xor(gs, 32);   // halves hold complementary u-sets
        cs += __shfl_xor(cs, 32);
        G = gs;
        C = cs + b2[q];
    }

    const float* xq = x + q * 8;

    // prime iter 0: tile0 = rows b0+u, tile1 = rows b0+32+u (dup across halves)
    float4 c00, c01, c10, c11;
    {
        const float* p0 = xq + (size_t)(bx * 512 + u) * 1024;
        const float* p1 = xq + (size_t)(bx * 512 + 32 + u) * 1024;
        c00 = ((const float4*)p0)[0]; c01 = ((const float4*)p0)[1];
        c10 = ((const float4*)p1)[0]; c11 = ((const float4*)p1)[1];
    }

    #pragma unroll 1
    for (int it = 0; it < 8; ++it) {
        const int b0 = it * 64;   // row offset within the block's band

        // prefetch next iter (last re-reads current; L2-hot, discarded).
        // No barrier in the loop -> these stay genuinely async.
        const int bn = (it < 7) ? b0 + 64 : b0;
        const float* pn0 = xq + (size_t)(bx * 512 + bn + u) * 1024;
        const float* pn1 = xq + (size_t)(bx * 512 + bn + 32 + u) * 1024;
        float4 n00 = ((const float4*)pn0)[0], n01 = ((const float4*)pn0)[1];
        float4 n10 = ((const float4*)pn1)[0], n11 = ((const float4*)pn1)[1];

        // bf16 convert (hi only; W1 lo-term carries the correction)
        short8 xa = cvt8(c00, c01);
        short8 xb = cvt8(c10, c11);

        // two independent MFMA chains, C-in = b1
        f32x16 acc0 = __builtin_amdgcn_mfma_f32_32x32x16_bf16(wfrag, xa, biasr, 0, 0, 0);
        f32x16 acc1 = __builtin_amdgcn_mfma_f32_32x32x16_bf16(wfrag, xb, biasr, 0, 0, 0);

        float res0 = finish(acc0, g2r, G, C);
        float res1 = finish(acc1, g2r, G, C);

        // bare LDS writes — visibility deferred to the single post-loop barrier
        if (half == 0) {
            lout[(b0 + u) * 5 + w]      = res0;
            lout[(b0 + 32 + u) * 5 + w] = res1;
        }

        c00 = n00; c01 = n01; c10 = n10; c11 = n11;
    }

    __syncthreads();   // the ONLY barrier: make all lout writes visible

    // ---- gather/store phase: 512 rows, 2 per thread, float4 each ----
    {
        const int r0 = tid;
        const int r1 = tid + 256;
        float4 o0, o1;
        o0.x = lout[r0 * 5 + 0]; o0.y = lout[r0 * 5 + 1];
        o0.z = lout[r0 * 5 + 2]; o0.w = lout[r0 * 5 + 3];
        o1.x = lout[r1 * 5 + 0]; o1.y = lout[r1 * 5 + 1];
        o1.z = lout[r1 * 5 + 2]; o1.w = lout[r1 * 5 + 3];
        *(float4*)(out + (size_t)(bx * 512 + r0) * 128 + qt * 4) = o0;
        *(float4*)(out + (size_t)(bx * 512 + r1) * 128 + qt * 4) = o1;
    }
}

extern "C" void kernel_launch(void* const* d_in, const int* in_sizes, int n_in,
                              void* d_out, int out_size, void* d_ws, size_t ws_size,
                              hipStream_t stream) {
    const float* x     = (const float*)d_in[0];
    const float* W1    = (const float*)d_in[1];
    const float* b1    = (const float*)d_in[2];
    const float* gamma = (const float*)d_in[3];
    const float* beta  = (const float*)d_in[4];
    const float* W2    = (const float*)d_in[5];
    const float* b2    = (const float*)d_in[6];
    float* out = (float*)d_out;

    dim3 grid(32, 32);   // (512-row bands, q-tiles of 4)
    divenc_mfma<<<grid, 256, 0, stream>>>(x, W1, b1, gamma, beta, W2, b2, out);
}

// Round 10
// 31.803 us; speedup vs baseline: 1.0127x; 1.0127x over previous
//
#include <hip/hip_runtime.h>

// DivEncLayer via MFMA — r6 compute core, barrier-free loop, DEPTH-2 prefetch.
// Per (b,q): h = elu(x[b,q*8:+8]@W1[q] + b1[q]); LN(h); out = h@W2[q]+b2[q].
// B=16384, Q=128, S=8, U=32.
//
// v_mfma_f32_32x32x16_bf16 operand mapping (validated rounds 2-9):
//   A: lane l, reg j -> A[l&31][j + 8*(l>>5)]
//   B: lane l, reg j -> B[j + 8*(l>>5)][l&31]
//   D: lane l, reg r -> row u=(r&3)+8*(r>>2)+4*(l>>5), col b=l&31
// Packed A-frag: lanes<32 = bf16(W1^T) (k=0..7), lanes>=32 = bf16(W1-hi) (k=8..15).
// B duplicates each row across lane-halves (addressed by u=ln&31):
// D = (whi+wlo)*xhi + C-in, C-in = b1 (fp32 exact). x is bf16-hi only.
// LN+Dense2 folded: out = rsqrt(var+eps)*(dot(e,g2) - mu*G) + C.
//
// r9 post-mortem: ~1000 cyc stall/iter = load latency (cold x ~500-900 cyc)
// vs 1-iter prefetch distance (~550 cyc). Fix: 2-deep software pipeline
// (cur/nx/nn named rotation, static indexing). No in-loop barriers or global
// stores (r9-validated); ONE barrier then a batched gather/store phase.
// Block = 4 waves = 4 consecutive q, 8 iters x 64 contiguous rows.
// Grid (32,32) = 1024 blocks. launch_bounds(256,2): 256-VGPR budget so the
// compiler keeps both in-flight load sets live instead of serializing.

typedef __attribute__((ext_vector_type(8))) short short8;    // 8 bf16
typedef __attribute__((ext_vector_type(16))) float f32x16;

__device__ __forceinline__ short fbits(__bf16 b) { return __builtin_bit_cast(short, b); }

__device__ __forceinline__ float elu1(float v) {
    return v > 0.f ? v : __expf(v) - 1.f;
}

__device__ __forceinline__ short8 cvt8(const float4& a, const float4& b) {
    short8 r;
    r[0] = fbits((__bf16)a.x); r[1] = fbits((__bf16)a.y);
    r[2] = fbits((__bf16)a.z); r[3] = fbits((__bf16)a.w);
    r[4] = fbits((__bf16)b.x); r[5] = fbits((__bf16)b.y);
    r[6] = fbits((__bf16)b.z); r[7] = fbits((__bf16)b.w);
    return r;
}

__device__ __forceinline__ float finish(const f32x16& acc, const f32x16& g2r,
                                        float G, float C) {
    float sum = 0.f, ss = 0.f, dot = 0.f;
    #pragma unroll
    for (int r = 0; r < 16; ++r) {
        float e = elu1(acc[r]);
        sum += e;
        ss  = fmaf(e, e, ss);
        dot = fmaf(e, g2r[r], dot);
    }
    sum += __shfl_xor(sum, 32);
    ss  += __shfl_xor(ss, 32);
    dot += __shfl_xor(dot, 32);
    float mu  = sum * 0.03125f;
    float var = fmaf(-mu, mu, ss * 0.03125f);
    float inv = rsqrtf(var + 1e-3f);
    return fmaf(inv, fmaf(-mu, G, dot), C);
}

__global__ __launch_bounds__(256, 2) void divenc_mfma(
    const float* __restrict__ x,      // (16384, 1024)
    const float* __restrict__ W1,     // (128, 8, 32)
    const float* __restrict__ b1,     // (128, 32)
    const float* __restrict__ gamma,  // (128, 32)
    const float* __restrict__ beta,   // (128, 32)
    const float* __restrict__ W2,     // (128, 32)
    const float* __restrict__ b2,     // (128,)
    float* __restrict__ out)          // (16384, 128)
{
    __shared__ float lout[512 * 5];   // [row][q-slot], stride 5 (10 KiB)

    const int tid  = threadIdx.x;
    const int w    = tid >> 6;
    const int ln   = tid & 63;
    const int u    = ln & 31;
    const int half = ln >> 5;
    const int qt   = blockIdx.y;      // 0..31
    const int q    = qt * 4 + w;
    const int bx   = blockIdx.x;      // 0..31; block covers rows bx*512..+511

    // ---- A-frag: lanes<32 = whi (k=0..7), lanes>=32 = wlo (k=8..15) ----
    short8 wfrag;
    #pragma unroll
    for (int j = 0; j < 8; ++j) {
        float f  = W1[q * 256 + j * 32 + u];
        __bf16 h = (__bf16)f;
        wfrag[j] = half ? fbits((__bf16)(f - (float)h)) : fbits(h);
    }

    // ---- params: biasr (MFMA C-in) + g2r in regs, vector loads ----
    f32x16 biasr, g2r;
    float G, C;
    {
        float gs = 0.f, cs = 0.f;
        #pragma unroll
        for (int c = 0; c < 4; ++c) {
            const int ub = q * 32 + 4 * half + 8 * c;
            float4 b1v = *(const float4*)&b1[ub];
            float4 gav = *(const float4*)&gamma[ub];
            float4 w2v = *(const float4*)&W2[ub];
            float4 bev = *(const float4*)&beta[ub];
            #pragma unroll
            for (int j = 0; j < 4; ++j) {
                float g2 = ((const float*)&gav)[j] * ((const float*)&w2v)[j];
                biasr[4 * c + j] = ((const float*)&b1v)[j];
                g2r[4 * c + j]   = g2;
                gs += g2;
                cs += ((const float*)&bev)[j] * ((const float*)&w2v)[j];
            }
        }
        gs += __shfl_xor(gs, 32);   // halves hold complementary u-sets
        cs += __shfl_xor(cs, 32);
        G = gs;
        C = cs + b2[q];
    }

    const float* xq = x + q * 8;
    const size_t rowbase = (size_t)(bx * 512 + u);

    // ---- prime: tiles 0 and 1 in flight (depth-2 pipeline) ----
    float4 c00, c01, c10, c11;   // current tile (iter it)
    float4 x00, x01, x10, x11;   // next tile    (iter it+1)
    {
        const float* p0 = xq + (rowbase +  0) * 1024;
        const float* p1 = xq + (rowbase + 32) * 1024;
        const float* p2 = xq + (rowbase + 64) * 1024;
        const float* p3 = xq + (rowbase + 96) * 1024;
        c00 = ((const float4*)p0)[0]; c01 = ((const float4*)p0)[1];
        c10 = ((const float4*)p1)[0]; c11 = ((const float4*)p1)[1];
        x00 = ((const float4*)p2)[0]; x01 = ((const float4*)p2)[1];
        x10 = ((const float4*)p3)[0]; x11 = ((const float4*)p3)[1];
    }

    #pragma unroll 1
    for (int it = 0; it < 8; ++it) {
        const int b0 = it * 64;   // row offset within the block's band

        // issue loads for iter it+2 (beyond end: re-read current, discarded)
        const int bn = (it < 6) ? b0 + 128 : b0;
        const float* pn0 = xq + (rowbase + bn) * 1024;
        const float* pn1 = xq + (rowbase + bn + 32) * 1024;
        float4 n00 = ((const float4*)pn0)[0], n01 = ((const float4*)pn0)[1];
        float4 n10 = ((const float4*)pn1)[0], n11 = ((const float4*)pn1)[1];

        // compute on current tile (loaded 2 iterations ago)
        short8 xa = cvt8(c00, c01);
        short8 xb = cvt8(c10, c11);

        f32x16 acc0 = __builtin_amdgcn_mfma_f32_32x32x16_bf16(wfrag, xa, biasr, 0, 0, 0);
        f32x16 acc1 = __builtin_amdgcn_mfma_f32_32x32x16_bf16(wfrag, xb, biasr, 0, 0, 0);

        float res0 = finish(acc0, g2r, G, C);
        float res1 = finish(acc1, g2r, G, C);

        // bare LDS writes — visibility deferred to the single post-loop barrier
        if (half == 0) {
            lout[(b0 + u) * 5 + w]      = res0;
            lout[(b0 + 32 + u) * 5 + w] = res1;
        }

        // rotate pipeline: cur <- nx, nx <- incoming
        c00 = x00; c01 = x01; c10 = x10; c11 = x11;
        x00 = n00; x01 = n01; x10 = n10; x11 = n11;
    }

    __syncthreads();   // the ONLY barrier: make all lout writes visible

    // ---- gather/store phase: 512 rows, 2 per thread, float4 each ----
    {
        const int r0 = tid;
        const int r1 = tid + 256;
        float4 o0, o1;
        o0.x = lout[r0 * 5 + 0]; o0.y = lout[r0 * 5 + 1];
        o0.z = lout[r0 * 5 + 2]; o0.w = lout[r0 * 5 + 3];
        o1.x = lout[r1 * 5 + 0]; o1.y = lout[r1 * 5 + 1];
        o1.z = lout[r1 * 5 + 2]; o1.w = lout[r1 * 5 + 3];
        *(float4*)(out + (size_t)(bx * 512 + r0) * 128 + qt * 4) = o0;
        *(float4*)(out + (size_t)(bx * 512 + r1) * 128 + qt * 4) = o1;
    }
}

extern "C" void kernel_launch(void* const* d_in, const int* in_sizes, int n_in,
                              void* d_out, int out_size, void* d_ws, size_t ws_size,
                              hipStream_t stream) {
    const float* x     = (const float*)d_in[0];
    const float* W1    = (const float*)d_in[1];
    const float* b1    = (const float*)d_in[2];
    const float* gamma = (const float*)d_in[3];
    const float* beta  = (const float*)d_in[4];
    const float* W2    = (const float*)d_in[5];
    const float* b2    = (const float*)d_in[6];
    float* out = (float*)d_out;

    dim3 grid(32, 32);   // (512-row bands, q-tiles of 4)
    divenc_mfma<<<grid, 256, 0, stream>>>(x, W1, b1, gamma, beta, W2, b2, out);
}

// Round 11
// 28.657 us; speedup vs baseline: 1.1239x; 1.1098x over previous
//
#include <hip/hip_runtime.h>

// DivEncLayer via MFMA — block-cooperative COALESCED LDS staging of x.
// Per (b,q): h = elu(x[b,q*8:+8]@W1[q] + b1[q]); LN(h); out = h@W2[q]+b2[q].
// B=16384, Q=128, S=8, U=32.
//
// r10 post-mortem: all prior variants issued per-lane strided loads (32
// distinct half-used 64B lines per wave-instr, per wave) -> TA/L1 line-request
// front-end saturated (~4 lines/cyc/CU); VALUBusy pinned ~35% regardless of
// TLP/ILP/barriers. Fix: block's x-panel (64 rows x 128 B, columns of all 4
// q's contiguous) is staged ONCE per block per iter with fully-coalesced
// float4 loads (8 thr/row, all bytes of all lines used), cvt to bf16, LDS
// rows padded to 80 B (16B-aligned frags, <=4-way bank conflict).
//
// v_mfma_f32_32x32x16_bf16 mapping (validated r2-r10):
//   A: lane l, reg j -> A[l&31][j + 8*(l>>5)]   B: lane l, reg j -> B[j+8*(l>>5)][l&31]
//   D: lane l, reg r -> row u=(r&3)+8*(r>>2)+4*(l>>5), col b=l&31
// Packed A-frag: lanes<32 = bf16(W1^T) (k<8), lanes>=32 = bf16(W1-hi) (k>=8).
// B-frag: lane reads staged row u=l&31 (halves broadcast-dup) -> one ds_read_b128.
// D = (whi+wlo)*xhi + b1 (C-in, fp32). LN+Dense2 folded:
//   out = rsqrt(var+eps)*(dot(e,g2) - mu*G) + C; g2=gamma*W2, G=sum g2, C=sum(beta*W2)+b2.
// Block = 4 waves = q-tile. 4 iters x 64 rows = 256-row band. Grid (64,32)=2048.
// lout gather -> one float4 store per row (write-exact, proven r2/r6).

typedef __attribute__((ext_vector_type(8))) short short8;    // 8 bf16
typedef __attribute__((ext_vector_type(16))) float f32x16;

#define XS_STRIDE 40   // shorts per staged row (80 B): b128-aligned, 4-way max

__device__ __forceinline__ short fbits(__bf16 b) { return __builtin_bit_cast(short, b); }

__device__ __forceinline__ float elu1(float v) {
    return v > 0.f ? v : __expf(v) - 1.f;
}

__device__ __forceinline__ short4 cvt4(float4 v) {
    short4 r;
    r.x = fbits((__bf16)v.x); r.y = fbits((__bf16)v.y);
    r.z = fbits((__bf16)v.z); r.w = fbits((__bf16)v.w);
    return r;
}

__device__ __forceinline__ float finish(const f32x16& acc, const f32x16& g2r,
                                        float G, float C) {
    float sum = 0.f, ss = 0.f, dot = 0.f;
    #pragma unroll
    for (int r = 0; r < 16; ++r) {
        float e = elu1(acc[r]);
        sum += e;
        ss  = fmaf(e, e, ss);
        dot = fmaf(e, g2r[r], dot);
    }
    sum += __shfl_xor(sum, 32);
    ss  += __shfl_xor(ss, 32);
    dot += __shfl_xor(dot, 32);
    float mu  = sum * 0.03125f;
    float var = fmaf(-mu, mu, ss * 0.03125f);
    float inv = rsqrtf(var + 1e-3f);
    return fmaf(inv, fmaf(-mu, G, dot), C);
}

__global__ __launch_bounds__(256, 4) void divenc_mfma(
    const float* __restrict__ x,      // (16384, 1024)
    const float* __restrict__ W1,     // (128, 8, 32)
    const float* __restrict__ b1,     // (128, 32)
    const float* __restrict__ gamma,  // (128, 32)
    const float* __restrict__ beta,   // (128, 32)
    const float* __restrict__ W2,     // (128, 32)
    const float* __restrict__ b2,     // (128,)
    float* __restrict__ out)          // (16384, 128)
{
    __shared__ short xs[2][64 * XS_STRIDE];   // staged bf16 panels, 5 KB each
    __shared__ float lout[256 * 5];           // results, padded stride 5

    const int tid  = threadIdx.x;
    const int w    = tid >> 6;
    const int ln   = tid & 63;
    const int u    = ln & 31;
    const int half = ln >> 5;
    const int qt   = blockIdx.y;      // 0..31
    const int q    = qt * 4 + w;
    const int bx   = blockIdx.x;      // 0..63; band = rows bx*256..+255
    const int band = bx * 256;

    // staging role: thread t covers panel chunks t and t+256
    // (chunk-flat f: row = f>>3 (64 rows), chunk = f&7 (8 x 16B per 128B row))
    const int srow0 = tid >> 3;            // 0..31
    const int srow1 = srow0 + 32;          // 32..63
    const int schk  = tid & 7;
    const float* xpan = x + qt * 32 + schk * 4;   // + row*1024 added per use

    // ---- A-frag: lanes<32 = whi (k=0..7), lanes>=32 = wlo (k=8..15) ----
    short8 wfrag;
    #pragma unroll
    for (int j = 0; j < 8; ++j) {
        float f  = W1[q * 256 + j * 32 + u];
        __bf16 h = (__bf16)f;
        wfrag[j] = half ? fbits((__bf16)(f - (float)h)) : fbits(h);
    }

    // ---- params: biasr (MFMA C-in) + g2r in regs, vector loads ----
    f32x16 biasr, g2r;
    float G, C;
    {
        float gs = 0.f, cs = 0.f;
        #pragma unroll
        for (int c = 0; c < 4; ++c) {
            const int ub = q * 32 + 4 * half + 8 * c;
            float4 b1v = *(const float4*)&b1[ub];
            float4 gav = *(const float4*)&gamma[ub];
            float4 w2v = *(const float4*)&W2[ub];
            float4 bev = *(const float4*)&beta[ub];
            #pragma unroll
            for (int j = 0; j < 4; ++j) {
                float g2 = ((const float*)&gav)[j] * ((const float*)&w2v)[j];
                biasr[4 * c + j] = ((const float*)&b1v)[j];
                g2r[4 * c + j]   = g2;
                gs += g2;
                cs += ((const float*)&bev)[j] * ((const float*)&w2v)[j];
            }
        }
        gs += __shfl_xor(gs, 32);   // halves hold complementary u-sets
        cs += __shfl_xor(cs, 32);
        G = gs;
        C = cs + b2[q];
    }

    // ---- prologue: stage iter-0 panel (coalesced: 8 thr cover one 128B row) ----
    {
        float4 g0 = *(const float4*)(xpan + (size_t)(band + srow0) * 1024);
        float4 g1 = *(const float4*)(xpan + (size_t)(band + srow1) * 1024);
        *(short4*)&xs[0][srow0 * XS_STRIDE + schk * 4] = cvt4(g0);
        *(short4*)&xs[0][srow1 * XS_STRIDE + schk * 4] = cvt4(g1);
    }
    __syncthreads();

    #pragma unroll 1
    for (int it = 0; it < 4; ++it) {
        const int cur = it & 1;
        const int b0  = it * 64;        // row offset within band

        // issue next panel's coalesced loads early (hidden under compute)
        float4 g0, g1;
        if (it < 3) {
            g0 = *(const float4*)(xpan + (size_t)(band + b0 + 64 + srow0) * 1024);
            g1 = *(const float4*)(xpan + (size_t)(band + b0 + 64 + srow1) * 1024);
        }

        // B-frags from staged panel: one b128 each, halves broadcast-dup
        short8 xa = *(const short8*)&xs[cur][u * XS_STRIDE + w * 8];
        short8 xb = *(const short8*)&xs[cur][(u + 32) * XS_STRIDE + w * 8];

        f32x16 acc0 = __builtin_amdgcn_mfma_f32_32x32x16_bf16(wfrag, xa, biasr, 0, 0, 0);
        f32x16 acc1 = __builtin_amdgcn_mfma_f32_32x32x16_bf16(wfrag, xb, biasr, 0, 0, 0);

        float res0 = finish(acc0, g2r, G, C);
        float res1 = finish(acc1, g2r, G, C);

        // bare LDS result writes (visibility via the per-iter barrier)
        if (half == 0) {
            lout[(b0 + u) * 5 + w]      = res0;
            lout[(b0 + 32 + u) * 5 + w] = res1;
        }

        // write next panel (waits only on g0/g1), then the iter barrier
        if (it < 3) {
            *(short4*)&xs[cur ^ 1][srow0 * XS_STRIDE + schk * 4] = cvt4(g0);
            *(short4*)&xs[cur ^ 1][srow1 * XS_STRIDE + schk * 4] = cvt4(g1);
        }
        __syncthreads();
    }

    // ---- gather/store: 256 rows, one float4 per thread (write-exact) ----
    {
        float4 o;
        o.x = lout[tid * 5 + 0];
        o.y = lout[tid * 5 + 1];
        o.z = lout[tid * 5 + 2];
        o.w = lout[tid * 5 + 3];
        *(float4*)(out + (size_t)(band + tid) * 128 + qt * 4) = o;
    }
}

extern "C" void kernel_launch(void* const* d_in, const int* in_sizes, int n_in,
                              void* d_out, int out_size, void* d_ws, size_t ws_size,
                              hipStream_t stream) {
    const float* x     = (const float*)d_in[0];
    const float* W1    = (const float*)d_in[1];
    const float* b1    = (const float*)d_in[2];
    const float* gamma = (const float*)d_in[3];
    const float* beta  = (const float*)d_in[4];
    const float* W2    = (const float*)d_in[5];
    const float* b2    = (const float*)d_in[6];
    float* out = (float*)d_out;

    dim3 grid(64, 32);   // (256-row bands, q-tiles of 4) = 2048 blocks
    divenc_mfma<<<grid, 256, 0, stream>>>(x, W1, b1, gamma, beta, W2, b2, out);
}